// Round 2
// baseline (436.544 us; speedup 1.0000x reference)
//
#include <hip/hip_runtime.h>
#include <hip/hip_bf16.h>

#define B_ 8
#define S_ 2048
#define H_ 256
#define BS_ (B_*S_)

typedef __attribute__((ext_vector_type(8))) short bf16x8;
typedef __attribute__((ext_vector_type(4))) short bf16x4;
typedef __attribute__((ext_vector_type(4))) float f32x4;

static __device__ inline short f2bf(float f) {
  union { float f; unsigned int u; } a; a.f = f;
  unsigned int u = a.u;
  unsigned int r = (u + 0x7fffu + ((u >> 16) & 1u)) >> 16;
  return (short)r;
}

static __device__ inline f32x4 mfma16(bf16x8 a, bf16x8 b, f32x4 c) {
  return __builtin_amdgcn_mfma_f32_16x16x32_bf16(a, b, c, 0, 0, 0);
}

// ---------------------------------------------------------------------------
// Kernel 0: fp32 -> bf16 conversion of x, Wq, Wk, Wv into workspace.
// Grid-stride over float4 units.
// ---------------------------------------------------------------------------
#define NX4 (BS_ * H_ / 4)        // 1,048,576 float4 in x
#define NW4 (H_ * H_ / 4)         // 16,384 float4 per W
#define NTOT4 (NX4 + 3 * NW4)

__global__ __launch_bounds__(256) void cvt_bf16(
    const float* __restrict__ x,
    const float* __restrict__ Wq, const float* __restrict__ Wk,
    const float* __restrict__ Wv,
    short* __restrict__ xb, short* __restrict__ wqb,
    short* __restrict__ wkb, short* __restrict__ wvb)
{
  int stride = gridDim.x * blockDim.x;
  for (int i = blockIdx.x * blockDim.x + threadIdx.x; i < NTOT4; i += stride) {
    const float* src; short* dst; int off;
    if (i < NX4) { src = x; dst = xb; off = i; }
    else {
      int j = i - NX4;
      int w = j >> 14;            // / NW4
      off = j & (NW4 - 1);
      src = (w == 0) ? Wq : (w == 1) ? Wk : Wv;
      dst = (w == 0) ? wqb : (w == 1) ? wkb : wvb;
    }
    float4 v = *(const float4*)(src + off * 4);
    bf16x4 p;
    p[0] = f2bf(v.x); p[1] = f2bf(v.y); p[2] = f2bf(v.z); p[3] = f2bf(v.w);
    *(bf16x4*)(dst + off * 4) = p;
  }
}

// ---------------------------------------------------------------------------
// Kernel 1: Q = X Wq^T + bq ; K = X Wk^T + bk ; V (stored transposed per batch)
// grid (BS/64, 3), block 256. Wave w handles rows s0+16w..+16, all 256 cols.
// Bias added in fp32 (read directly from fp32 input), result stored bf16.
// ---------------------------------------------------------------------------
__global__ __launch_bounds__(256) void qkv_proj(
    const short* __restrict__ x,
    const short* __restrict__ Wq, const float* __restrict__ bq,
    const short* __restrict__ Wk, const float* __restrict__ bk,
    const short* __restrict__ Wv, const float* __restrict__ bv,
    short* __restrict__ Qo, short* __restrict__ Ko, short* __restrict__ VTo)
{
  const int tid  = threadIdx.x;
  const int wave = tid >> 6;
  const int lane = tid & 63;
  const int quad = lane >> 4;
  const int l16  = lane & 15;
  const int y    = blockIdx.y;

  const short* W    = (y == 0) ? Wq : (y == 1) ? Wk : Wv;
  const float* bias = (y == 0) ? bq : (y == 1) ? bk : bv;
  const int s0 = blockIdx.x * 64 + wave * 16;

  f32x4 zero = {0.f, 0.f, 0.f, 0.f};
  f32x4 acc[16];
#pragma unroll
  for (int i = 0; i < 16; i++) acc[i] = zero;

  const short* xrow = x + (s0 + l16) * H_ + quad * 8;
#pragma unroll
  for (int ks = 0; ks < 8; ks++) {
    bf16x8 a = *(const bf16x8*)(xrow + ks * 32);
#pragma unroll
    for (int nf = 0; nf < 16; nf++) {
      bf16x8 bb = *(const bf16x8*)(W + (nf * 16 + l16) * H_ + ks * 32 + quad * 8);
      acc[nf] = mfma16(a, bb, acc[nf]);
    }
  }

  if (y < 2) {
    short* dst = (y == 0) ? Qo : Ko;
#pragma unroll
    for (int nf = 0; nf < 16; nf++) {
      int col = nf * 16 + l16;
      float bvl = bias[col];
#pragma unroll
      for (int r = 0; r < 4; r++) {
        int row = s0 + quad * 4 + r;
        dst[row * H_ + col] = f2bf(acc[nf][r] + bvl);
      }
    }
  } else {
    // V transposed: VT[b][h][k], 4 consecutive k per lane -> 8B packed store
    int row0  = s0 + quad * 4;
    int b_idx = row0 >> 11;        // row0 / 2048
    int k0    = row0 & (S_ - 1);
#pragma unroll
    for (int nf = 0; nf < 16; nf++) {
      int col = nf * 16 + l16;     // h
      float bvl = bias[col];
      bf16x4 pk;
#pragma unroll
      for (int r = 0; r < 4; r++) pk[r] = f2bf(acc[nf][r] + bvl);
      *(bf16x4*)(VTo + (size_t)b_idx * H_ * S_ + (size_t)col * S_ + k0) = pk;
    }
  }
}

// ---------------------------------------------------------------------------
// Kernel 2: rcp_den[b][k] = 1 / sum_q exp( (Q K^T)[q][k] / 256 )
// grid 256 (8 b x 32 kblk), block 256. wg owns 64 k-columns, loops all q.
// ---------------------------------------------------------------------------
__global__ __launch_bounds__(256) void col_denom(
    const short* __restrict__ Q, const short* __restrict__ K,
    float* __restrict__ rcp_den)
{
  const int tid  = threadIdx.x;
  const int wave = tid >> 6;
  const int lane = tid & 63;
  const int quad = lane >> 4;
  const int l16  = lane & 15;
  const int b    = blockIdx.x >> 5;
  const int kblk = blockIdx.x & 31;
  const int colbase = kblk * 64;

  const short* Qb = Q + b * S_ * H_;
  const short* Kb = K + b * S_ * H_;

  f32x4 zero = {0.f, 0.f, 0.f, 0.f};
  float csum[4] = {0.f, 0.f, 0.f, 0.f};

  for (int q0 = 0; q0 < S_; q0 += 64) {
    f32x4 sacc[4];
#pragma unroll
    for (int nf = 0; nf < 4; nf++) sacc[nf] = zero;
    const short* qrow = Qb + (q0 + wave * 16 + l16) * H_ + quad * 8;
#pragma unroll
    for (int ks = 0; ks < 8; ks++) {
      bf16x8 a = *(const bf16x8*)(qrow + ks * 32);
#pragma unroll
      for (int nf = 0; nf < 4; nf++) {
        bf16x8 bb = *(const bf16x8*)(Kb + (colbase + nf * 16 + l16) * H_ + ks * 32 + quad * 8);
        sacc[nf] = mfma16(a, bb, sacc[nf]);
      }
    }
#pragma unroll
    for (int nf = 0; nf < 4; nf++) {
#pragma unroll
      for (int r = 0; r < 4; r++)
        csum[nf] += __expf(sacc[nf][r] * (1.0f / H_));
    }
  }

#pragma unroll
  for (int nf = 0; nf < 4; nf++) {
    csum[nf] += __shfl_xor(csum[nf], 16, 64);
    csum[nf] += __shfl_xor(csum[nf], 32, 64);
  }

  __shared__ float red[4][64];
  if (lane < 16) {
#pragma unroll
    for (int nf = 0; nf < 4; nf++) red[wave][nf * 16 + lane] = csum[nf];
  }
  __syncthreads();
  if (tid < 64) {
    float s = red[0][tid] + red[1][tid] + red[2][tid] + red[3][tid];
    rcp_den[b * S_ + colbase + tid] = 1.0f / s;
  }
}

// ---------------------------------------------------------------------------
// Kernel 3: out[b][q][h] = sum_k exp(s[q][k]/256) * rcp_den[k] * V[k][h]
// grid 256 (8 b x 32 qblk), block 256. wg owns 64 q-rows x 256 h.
// P transits C-layout -> LDS (stride 72) -> A-layout, per-wave region.
// Output stored fp32.
// ---------------------------------------------------------------------------
__global__ __launch_bounds__(256) void attn_out(
    const short* __restrict__ Q, const short* __restrict__ K,
    const short* __restrict__ VT, const float* __restrict__ rcp_den,
    float* __restrict__ out)
{
  const int tid  = threadIdx.x;
  const int wave = tid >> 6;
  const int lane = tid & 63;
  const int quad = lane >> 4;
  const int l16  = lane & 15;
  const int b    = blockIdx.x >> 5;
  const int qblk = blockIdx.x & 31;

  const short* Qb  = Q + b * S_ * H_;
  const short* Kb  = K + b * S_ * H_;
  const short* VTb = VT + (size_t)b * H_ * S_;
  const float* rd  = rcp_den + b * S_;
  const int rowq   = qblk * 64 + wave * 16;

  __shared__ short pbuf[4][16 * 72];
  short* pw = &pbuf[wave][0];

  // Hoist Q A-frags (constant across the k loop)
  bf16x8 afr[8];
#pragma unroll
  for (int ks = 0; ks < 8; ks++)
    afr[ks] = *(const bf16x8*)(Qb + (rowq + l16) * H_ + ks * 32 + quad * 8);

  f32x4 zero = {0.f, 0.f, 0.f, 0.f};
  f32x4 oacc[16];
#pragma unroll
  for (int i = 0; i < 16; i++) oacc[i] = zero;

  for (int kc = 0; kc < S_; kc += 64) {
    // S-tile: 16 q-rows x 64 k-cols
    f32x4 sacc[4];
#pragma unroll
    for (int nf = 0; nf < 4; nf++) sacc[nf] = zero;
#pragma unroll
    for (int ks = 0; ks < 8; ks++) {
#pragma unroll
      for (int nf = 0; nf < 4; nf++) {
        bf16x8 bb = *(const bf16x8*)(Kb + (kc + nf * 16 + l16) * H_ + ks * 32 + quad * 8);
        sacc[nf] = mfma16(afr[ks], bb, sacc[nf]);
      }
    }
    // exp, scale by rcp_den, write P to per-wave LDS (C-layout positions)
#pragma unroll
    for (int nf = 0; nf < 4; nf++) {
      float r_d = rd[kc + nf * 16 + l16];
      int col = nf * 16 + l16;
#pragma unroll
      for (int r = 0; r < 4; r++) {
        float p = __expf(sacc[nf][r] * (1.0f / H_)) * r_d;
        pw[(quad * 4 + r) * 72 + col] = f2bf(p);
      }
    }
    __syncthreads();  // conservative: guarantee LDS write->read ordering
    // PV: A from LDS (A-layout), B from VT (contiguous 16B)
#pragma unroll
    for (int st = 0; st < 2; st++) {
      bf16x8 pa = *(const bf16x8*)(pw + l16 * 72 + st * 32 + quad * 8);
#pragma unroll
      for (int nf2 = 0; nf2 < 16; nf2++) {
        bf16x8 vb = *(const bf16x8*)(VTb + (size_t)(nf2 * 16 + l16) * S_ + kc + st * 32 + quad * 8);
        oacc[nf2] = mfma16(pa, vb, oacc[nf2]);
      }
    }
    __syncthreads();  // protect pbuf before next iteration's writes
  }

#pragma unroll
  for (int nf2 = 0; nf2 < 16; nf2++) {
    int col = nf2 * 16 + l16;
#pragma unroll
    for (int r = 0; r < 4; r++) {
      int q = rowq + quad * 4 + r;
      out[((size_t)b * S_ + q) * H_ + col] = oacc[nf2][r];
    }
  }
}

extern "C" void kernel_launch(void* const* d_in, const int* in_sizes, int n_in,
                              void* d_out, int out_size, void* d_ws, size_t ws_size,
                              hipStream_t stream) {
  const float* x  = (const float*)d_in[0];
  const float* Wq = (const float*)d_in[1];
  const float* bq = (const float*)d_in[2];
  const float* Wk = (const float*)d_in[3];
  const float* bk = (const float*)d_in[4];
  const float* Wv = (const float*)d_in[5];
  const float* bv = (const float*)d_in[6];

  // Workspace layout (shorts unless noted):
  short* xb  = (short*)d_ws;                    // BS*H bf16     = 8 MiB
  short* wqb = xb  + (size_t)BS_ * H_;          // H*H bf16      = 128 KiB
  short* wkb = wqb + H_ * H_;
  short* wvb = wkb + H_ * H_;
  short* Qs  = wvb + H_ * H_;                   // 8 MiB
  short* Ks  = Qs  + (size_t)BS_ * H_;          // 8 MiB
  short* VT  = Ks  + (size_t)BS_ * H_;          // 8 MiB (transposed [b][h][k])
  float* rd  = (float*)(VT + (size_t)BS_ * H_); // 64 KiB
  float* outp = (float*)d_out;

  cvt_bf16<<<1024, 256, 0, stream>>>(x, Wq, Wk, Wv, xb, wqb, wkb, wvb);
  qkv_proj<<<dim3(BS_ / 64, 3), 256, 0, stream>>>(xb, wqb, bq, wkb, bk, wvb, bv, Qs, Ks, VT);
  col_denom<<<dim3(256), 256, 0, stream>>>(Qs, Ks, rd);
  attn_out<<<dim3(256), 256, 0, stream>>>(Qs, Ks, VT, rd, outp);
}